// Round 1
// baseline (1063.423 us; speedup 1.0000x reference)
//
#include <hip/hip_runtime.h>

// Eikonal 2D: |grad u| = f, u(256,256)=0, Godunov upwind, converged fixed point.
// Strategy: tiled FIM-style relaxation. Each 32x32 tile converges in LDS with a
// frozen halo (chaotic in-place updates, __syncthreads_or early exit); T outer
// kernel launches exchange halos via global memory. Monotone min-updates from
// BIG make any schedule safe (result always >= fixed point, non-increasing).

#define NG    512
#define TILE  32
#define BIGV  1e10f
#define SRC_I 256
#define SRC_J 256
#define KMAX  128   // inner relaxation passes per outer step (early-exit usually much sooner)
#define TOUT  36    // outer halo-exchange steps (tile grid is 16x16, source tile (8,8))

__global__ void eik_init(float* __restrict__ u) {
    int idx = blockIdx.x * blockDim.x + threadIdx.x;
    if (idx < NG * NG) u[idx] = (idx == SRC_I * NG + SRC_J) ? 0.0f : BIGV;
}

__global__ __launch_bounds__(TILE * TILE) void eik_tile(const float* __restrict__ f,
                                                        float* __restrict__ u) {
    __shared__ float su[TILE + 2][TILE + 2];

    const int tx = threadIdx.x;           // column within tile, 0..31
    const int ty = threadIdx.y;           // row within tile, 0..31
    const int gi = blockIdx.y * TILE + ty;
    const int gj = blockIdx.x * TILE + tx;
    const int gidx = gi * NG + gj;

    const float fh = f[gidx];             // f * h, h = 1

    // Load tile interior + plus-shaped halo (corners unused by the stencil).
    su[ty + 1][tx + 1] = u[gidx];
    if (ty == 0)        su[0][tx + 1]        = (gi > 0)      ? u[gidx - NG] : BIGV;
    if (ty == TILE - 1) su[TILE + 1][tx + 1] = (gi < NG - 1) ? u[gidx + NG] : BIGV;
    if (tx == 0)        su[ty + 1][0]        = (gj > 0)      ? u[gidx - 1]  : BIGV;
    if (tx == TILE - 1) su[ty + 1][TILE + 1] = (gj < NG - 1) ? u[gidx + 1]  : BIGV;
    __syncthreads();

    // Chaotic in-place relaxation to the tile-local fixed point (halo frozen).
    // Monotone: every write only decreases a cell; reads see old-or-new values,
    // both >= the global fixed point, so convergence target is unaffected.
    for (int it = 0; it < KMAX; ++it) {
        float a   = fminf(su[ty][tx + 1], su[ty + 2][tx + 1]);   // i-direction upwind min
        float b   = fminf(su[ty + 1][tx], su[ty + 1][tx + 2]);   // j-direction upwind min
        float cur = su[ty + 1][tx + 1];
        float d   = fabsf(a - b);
        float un;
        if (d >= fh) {
            un = fminf(a, b) + fh;                                // 1D update
        } else {
            un = 0.5f * (a + b + sqrtf(fmaxf(2.0f * fh * fh - d * d, 0.0f)));  // 2D root
        }
        int ch = (un < cur) ? 1 : 0;
        if (ch) su[ty + 1][tx + 1] = un;   // source cell stays 0: un > 0 => never < cur
        if (!__syncthreads_or(ch)) break;  // tile at local fixed point -> done
    }

    u[gidx] = su[ty + 1][tx + 1];
}

extern "C" void kernel_launch(void* const* d_in, const int* in_sizes, int n_in,
                              void* d_out, int out_size, void* d_ws, size_t ws_size,
                              hipStream_t stream) {
    const float* f = (const float*)d_in[0];
    float* u = (float*)d_out;   // use d_out directly as the solution buffer

    eik_init<<<(NG * NG + 1023) / 1024, 1024, 0, stream>>>(u);

    dim3 grid(NG / TILE, NG / TILE);   // 16 x 16 tiles
    dim3 block(TILE, TILE);            // 1024 threads, one per cell
    for (int t = 0; t < TOUT; ++t) {
        eik_tile<<<grid, block, 0, stream>>>(f, u);
    }
}

// Round 2
// 878.029 us; speedup vs baseline: 1.2111x; 1.2111x over previous
//
#include <hip/hip_runtime.h>

// Eikonal 2D: |grad u| = f, u(256,256)=0, Godunov upwind, converged fixed point.
//
// Persistent-kernel chaotic relaxation: one block per 32x32 tile, one thread per
// cell, interior resident in (volatile) LDS for the whole solve. Each round:
//   1. edge threads refresh their halo value from neighbor tiles' published
//      edges in global u (device-scope loads; per-XCD L2s are not coherent),
//   2. K barrier-free Jacobi iterations on volatile LDS (monotone min-updates
//      from BIG make any racy schedule safe: values only decrease, any stale
//      read is >= fixed point),
//   3. edge threads publish their value device-scope; one __syncthreads bounds
//      intra-block wave drift.
// Fixed ROUNDS*KIN = 1200 virtual Jacobi steps >= reference's 1100 budget
// (worst path ~700 cells + ~K/2 stall per tile-boundary crossing).
// Halo values feed only the edge thread's own update -> kept in registers.

#define NG    512
#define TILE  32
#define BIGV  1e10f
#define SRC_I 256
#define SRC_J 256
#define KIN   8     // inner chaotic Jacobi iterations per round
#define ROUNDS 150  // rounds; ROUNDS*KIN = 1200 virtual sweeps

__global__ void eik_init(float* __restrict__ u) {
    int idx = blockIdx.x * blockDim.x + threadIdx.x;
    if (idx < NG * NG) u[idx] = (idx == SRC_I * NG + SRC_J) ? 0.0f : BIGV;
}

__global__ __launch_bounds__(TILE * TILE) void eik_persist(const float* __restrict__ f,
                                                           float* __restrict__ u) {
    // 34 rows x 32 cols: rows 0 and 33 are never written; reads that land there
    // (or wrap a row via tx+/-1) are boundary-select garbage, discarded by the
    // cndmask before use. Stride-32 rows: 2 lanes/bank for wave64 = conflict-free.
    __shared__ float su_[(TILE + 2) * TILE];
    volatile float* su = su_;
#define S(r, c) su[((r) + 1) * TILE + (c)]

    const int tx = threadIdx.x;            // col in tile
    const int ty = threadIdx.y;            // row in tile
    const int gi = blockIdx.y * TILE + ty;
    const int gj = blockIdx.x * TILE + tx;
    const int gidx = gi * NG + gj;

    const float fh = f[gidx];              // f * h, h = 1

    const bool etop = (ty == 0),        ebot = (ty == TILE - 1);
    const bool elft = (tx == 0),        ergt = (tx == TILE - 1);
    const bool edge = etop | ebot | elft | ergt;
    const bool hastop = (gi > 0),       hasbot = (gi < NG - 1);
    const bool haslft = (gj > 0),       hasrgt = (gj < NG - 1);

    float v = (gidx == SRC_I * NG + SRC_J) ? 0.0f : BIGV;
    S(ty, tx) = v;
    __syncthreads();  // interior visible to all waves before round 0

    for (int r = 0; r < ROUNDS; ++r) {
        // 1. halo refresh (registers; each halo value is consumed only by the
        //    edge thread that loads it). Device-scope: neighbor tile may be on
        //    another XCD.
        float hN = BIGV, hS = BIGV, hW = BIGV, hE = BIGV;
        if (etop && hastop) hN = __hip_atomic_load(&u[gidx - NG], __ATOMIC_RELAXED, __HIP_MEMORY_SCOPE_AGENT);
        if (ebot && hasbot) hS = __hip_atomic_load(&u[gidx + NG], __ATOMIC_RELAXED, __HIP_MEMORY_SCOPE_AGENT);
        if (elft && haslft) hW = __hip_atomic_load(&u[gidx - 1],  __ATOMIC_RELAXED, __HIP_MEMORY_SCOPE_AGENT);
        if (ergt && hasrgt) hE = __hip_atomic_load(&u[gidx + 1],  __ATOMIC_RELAXED, __HIP_MEMORY_SCOPE_AGENT);

        // 2. chaotic barrier-free Jacobi on volatile LDS
#pragma unroll
        for (int k = 0; k < KIN; ++k) {
            float up = etop ? hN : S(ty - 1, tx);
            float dn = ebot ? hS : S(ty + 1, tx);
            float lf = elft ? hW : S(ty, tx - 1);
            float rt = ergt ? hE : S(ty, tx + 1);
            float a = fminf(up, dn);
            float b = fminf(lf, rt);
            float d = fabsf(a - b);
            float un;
            if (d >= fh) {
                un = fminf(a, b) + fh;                                          // 1D update
            } else {
                un = 0.5f * (a + b + sqrtf(fmaxf(2.0f * fh * fh - d * d, 0.0f))); // 2D root
            }
            if (un < v) {  // source cell: un > 0 == v, never taken
                v = un;
                S(ty, tx) = v;
            }
        }

        // 3. publish edges for neighbor tiles
        if (edge) __hip_atomic_store(&u[gidx], v, __ATOMIC_RELAXED, __HIP_MEMORY_SCOPE_AGENT);
        __syncthreads();  // bound wave drift to <= KIN iterations per round
    }

    u[gidx] = v;
#undef S
}

extern "C" void kernel_launch(void* const* d_in, const int* in_sizes, int n_in,
                              void* d_out, int out_size, void* d_ws, size_t ws_size,
                              hipStream_t stream) {
    const float* f = (const float*)d_in[0];
    float* u = (float*)d_out;   // solution buffer; also the halo-exchange medium

    eik_init<<<(NG * NG + 1023) / 1024, 1024, 0, stream>>>(u);

    dim3 grid(NG / TILE, NG / TILE);   // 16 x 16 tiles = 256 blocks, all co-resident
    dim3 block(TILE, TILE);            // 1024 threads = 16 waves
    eik_persist<<<grid, block, 0, stream>>>(f, u);
}

// Round 3
// 489.340 us; speedup vs baseline: 2.1732x; 1.7943x over previous
//
#include <hip/hip_runtime.h>

// Eikonal 2D: |grad u| = f, u(256,256)=0, Godunov upwind, converged fixed point.
//
// Persistent-kernel relaxation, 1 block per 32x32 tile, 4 horizontally-packed
// cells per thread (float4 in registers, tile interior in LDS). Per round:
// load halo (device-scope; per-XCD L2s not coherent), KIN barrier-separated
// Jacobi iterations with in-quad alternating Gauss-Seidel (horizontal info
// moves 4 cells/iter, vertical 1/iter), publish edges device-scope.
// Monotone min-updates from BIG make racy/stale reads harmless (any schedule
// converges to the same fixed point from above). ROUNDS*KIN = 896 virtual
// sweeps vs worst dependency chain ~450-500 (~1.8x margin). Uniform work per
// block (no early exit) keeps blocks in rough lockstep so a fixed round count
// is safe; under-convergence would leave 1e10 cells (loudly caught).

#define NG     512
#define TILEH  32
#define TILEW  32
#define BIGV   1e10f
#define SRC_I  256
#define SRC_J  256
#define KIN    16
#define ROUNDS 56

__global__ void eik_init(float* __restrict__ u) {
    int idx = blockIdx.x * blockDim.x + threadIdx.x;
    if (idx < NG * NG) u[idx] = (idx == SRC_I * NG + SRC_J) ? 0.0f : BIGV;
}

__global__ __launch_bounds__(256) void eik_persist(const float* __restrict__ f,
                                                   float* __restrict__ u) {
    __shared__ float S[TILEH][TILEW];   // 4 KB, interior only (halo in registers)

    const int tx = threadIdx.x;         // quad index 0..7
    const int ty = threadIdx.y;         // row 0..31
    const int c0 = 4 * tx;
    const int gi = blockIdx.y * TILEH + ty;
    const int gj = blockIdx.x * TILEW + c0;
    const int base = gi * NG + gj;

    const float4 f4 = *(const float4*)(f + base);
    float fh[4] = {f4.x, f4.y, f4.z, f4.w};
    float fh2[4];
#pragma unroll
    for (int k = 0; k < 4; ++k) fh2[k] = 2.0f * fh[k] * fh[k];

    float v[4];
#pragma unroll
    for (int k = 0; k < 4; ++k)
        v[k] = (gi == SRC_I && (gj + k) == SRC_J) ? 0.0f : BIGV;

    const bool etop = (ty == 0), ebot = (ty == TILEH - 1);
    const bool elft = (tx == 0), ergt = (tx == 7);
    const bool hast = (gi > 0),  hasb = (gi < NG - 1);
    const bool hasl = (gj > 0),  hasr = (gj + 4 < NG);

    // clamped LDS coordinates (clamped lanes' reads are discarded by selects)
    const int rup = etop ? 0 : ty - 1;
    const int rdn = ebot ? TILEH - 1 : ty + 1;
    const int cl  = elft ? 0 : c0 - 1;
    const int cr  = ergt ? TILEW - 1 : c0 + 4;

    *(float4*)&S[ty][c0] = make_float4(v[0], v[1], v[2], v[3]);
    __syncthreads();

    for (int r = 0; r < ROUNDS; ++r) {
        // --- halo refresh (device scope, registers) ---
        float hN[4] = {BIGV, BIGV, BIGV, BIGV};
        float hS[4] = {BIGV, BIGV, BIGV, BIGV};
        float hW = BIGV, hE = BIGV;
        if (etop && hast) {
#pragma unroll
            for (int k = 0; k < 4; ++k)
                hN[k] = __hip_atomic_load(u + base - NG + k, __ATOMIC_RELAXED, __HIP_MEMORY_SCOPE_AGENT);
        }
        if (ebot && hasb) {
#pragma unroll
            for (int k = 0; k < 4; ++k)
                hS[k] = __hip_atomic_load(u + base + NG + k, __ATOMIC_RELAXED, __HIP_MEMORY_SCOPE_AGENT);
        }
        if (elft && hasl) hW = __hip_atomic_load(u + base - 1, __ATOMIC_RELAXED, __HIP_MEMORY_SCOPE_AGENT);
        if (ergt && hasr) hE = __hip_atomic_load(u + base + 4, __ATOMIC_RELAXED, __HIP_MEMORY_SCOPE_AGENT);

        // --- KIN barrier-separated iterations, in-quad alternating GS ---
        for (int it = 0; it < KIN; ++it) {
            float4 u4 = *(float4*)&S[rup][c0];
            float4 d4 = *(float4*)&S[rdn][c0];
            float lfe = elft ? hW : S[ty][cl];
            float rte = ergt ? hE : S[ty][cr];
            float up[4] = {u4.x, u4.y, u4.z, u4.w};
            float dn[4] = {d4.x, d4.y, d4.z, d4.w};
            if (etop) { up[0] = hN[0]; up[1] = hN[1]; up[2] = hN[2]; up[3] = hN[3]; }
            if (ebot) { dn[0] = hS[0]; dn[1] = hS[1]; dn[2] = hS[2]; dn[3] = hS[3]; }

            auto upd = [&](int k, float lf, float rt) {
                float a  = fminf(up[k], dn[k]);
                float b  = fminf(lf, rt);
                float d  = fabsf(a - b);
                float u1 = fminf(a, b) + fh[k];                  // 1D update
                float t  = fmaxf(fmaf(-d, d, fh2[k]), 0.0f);     // 2fh^2 - d^2
                float u2 = 0.5f * (a + b) + 0.5f * sqrtf(t);     // 2D root
                float un = (d >= fh[k]) ? u1 : u2;               // branch-free select
                v[k] = fminf(v[k], un);                          // source stays 0 (un > 0)
            };
            if ((it & 1) == 0) {          // rightward Gauss-Seidel within quad
                upd(0, lfe,  v[1]);
                upd(1, v[0], v[2]);
                upd(2, v[1], v[3]);
                upd(3, v[2], rte);
            } else {                      // leftward
                upd(3, v[2], rte);
                upd(2, v[1], v[3]);
                upd(1, v[0], v[2]);
                upd(0, lfe,  v[1]);
            }
            *(float4*)&S[ty][c0] = make_float4(v[0], v[1], v[2], v[3]);
            __syncthreads();   // defeats LDS register-caching; bounds drift
        }

        // --- publish tile edges (device scope) ---
        if (etop || ebot) {
#pragma unroll
            for (int k = 0; k < 4; ++k)
                __hip_atomic_store(u + base + k, v[k], __ATOMIC_RELAXED, __HIP_MEMORY_SCOPE_AGENT);
        }
        if (elft) __hip_atomic_store(u + base,     v[0], __ATOMIC_RELAXED, __HIP_MEMORY_SCOPE_AGENT);
        if (ergt) __hip_atomic_store(u + base + 3, v[3], __ATOMIC_RELAXED, __HIP_MEMORY_SCOPE_AGENT);
    }

    // final write: agent-scope b32 stores so same-address ordering with the
    // published edge stores is guaranteed (no L2-path vs LLC-path race)
#pragma unroll
    for (int k = 0; k < 4; ++k)
        __hip_atomic_store(u + base + k, v[k], __ATOMIC_RELAXED, __HIP_MEMORY_SCOPE_AGENT);
}

extern "C" void kernel_launch(void* const* d_in, const int* in_sizes, int n_in,
                              void* d_out, int out_size, void* d_ws, size_t ws_size,
                              hipStream_t stream) {
    const float* f = (const float*)d_in[0];
    float* u = (float*)d_out;   // solution buffer + halo-exchange medium

    eik_init<<<(NG * NG + 1023) / 1024, 1024, 0, stream>>>(u);

    dim3 grid(NG / TILEW, NG / TILEH);   // 16 x 16 tiles = 256 blocks (1/CU)
    dim3 block(8, 32);                   // 256 threads = 4 waves, 4 cells/thread
    eik_persist<<<grid, block, 0, stream>>>(f, u);
}